// Round 10
// baseline (609.286 us; speedup 1.0000x reference)
//
#include <hip/hip_runtime.h>
#include <hip/hip_fp16.h>
#include <hip/hip_cooperative_groups.h>
#include <cstdint>

namespace cg = cooperative_groups;

#define V_N 50000
#define E_N 800000
#define NODE_IN 128
#define EDGE_IN 16
#define HF 128
#define NEG_SLOPE 0.2f
#define NB_SCAN 196   // ceil(50000/256)

// ---- workspace layout (4-byte word offsets) ----
#define OFF_FT    0         // V*64 words (f16 ft, 128/node, head-major layout)
#define OFF_EL    3200000   // V*4
#define OFF_ER    3400000   // V*4
#define OFF_DEG   3600000   // V ints
#define OFF_ROW   3650000   // V+1 ints (+pad)
#define OFF_BSUM  3700004   // 256
#define OFF_REC   4500260   // E*4 words (uint4 records; 16B-aligned)
#define OFF_BFRAG 7700324   // 16384 words (16B-aligned)
// total ~7.72M words = 30.9 MB

typedef short bf16x8 __attribute__((ext_vector_type(8)));
typedef float f32x4 __attribute__((ext_vector_type(4)));

__device__ __forceinline__ unsigned short f2bf(float f) {
    unsigned u = __float_as_uint(f);
    u += 0x7fffu + ((u >> 16) & 1u);   // round-to-nearest-even
    return (unsigned short)(u >> 16);
}
__device__ __forceinline__ unsigned pk2(float lo, float hi) {
    return (unsigned)f2bf(lo) | ((unsigned)f2bf(hi) << 16);
}
__device__ __forceinline__ float bflo(unsigned w) { return __uint_as_float(w << 16); }
__device__ __forceinline__ float bfhi(unsigned w) { return __uint_as_float(w & 0xffff0000u); }

typedef __fp16 fp16x2 __attribute__((ext_vector_type(2)));
__device__ __forceinline__ unsigned pkh2(float a, float b) {
    fp16x2 h = __builtin_amdgcn_cvt_pkrtz(a, b);   // v_cvt_pkrtz_f16_f32
    return __builtin_bit_cast(unsigned, h);
}
__device__ __forceinline__ __half2 u2h(unsigned u) {
    return __builtin_bit_cast(__half2, u);
}
__device__ __forceinline__ unsigned h2u(__half2 h) {
    return __builtin_bit_cast(unsigned, h);
}

// k_prep: Bfrag conversion only (bf16 fragments of [Wn|Wr]).
__global__ void k_prep(const float* __restrict__ Wn,
                       const float* __restrict__ Wr,
                       unsigned* __restrict__ bfrag) {
    int g = blockIdx.x * 256 + threadIdx.x;
    if (g < 16384) {
        int c    = g >> 8;
        int lane = (g >> 2) & 63;
        int jp   = g & 3;
        int nt = c >> 2, ks = c & 3;
        int col = nt * 16 + (lane & 15);
        int k   = ks * 32 + (lane >> 4) * 8 + jp * 2;
        const float* W = (col < 128) ? Wn : Wr;
        int cc = col & 127;
        float x0 = W[(size_t)k * 128 + cc];
        float x1 = W[(size_t)(k + 1) * 128 + cc];
        bfrag[g] = pk2(x0, x1);
    }
}

// Node kernel (MFMA): 32 nodes x 256 cols per block; wave w == head w.
// ftw layout (head-major): uint idx = node*64 + head*16 + n15 (f16 pair tt=0,1)
__global__ __launch_bounds__(256) void k_node(
    const float* __restrict__ nf, const unsigned* __restrict__ bfragw,
    const float* __restrict__ attn_l, const float* __restrict__ attn_r,
    const float* __restrict__ bias,
    unsigned* __restrict__ ftw, float* __restrict__ el,
    float* __restrict__ er, float* __restrict__ out)
{
    __shared__ __align__(16) float sSf[32 * 140];
    unsigned short* sA = (unsigned short*)sSf;      // stride 136 bf16/row

    const int t = threadIdx.x;
    const int lane = t & 63;
    const int w = t >> 6;                            // == head
    const int nb = blockIdx.x * 32;
    const int n15 = lane & 15;
    const int q = lane >> 4;
    const unsigned short* bfrag = (const unsigned short*)bfragw;

    #pragma unroll
    for (int i = 0; i < 4; i++) {
        int f = t + i * 256;
        int node = f >> 5;
        int kc = (f & 31) * 4;
        float4 v = {0.f, 0.f, 0.f, 0.f};
        if (nb + node < V_N)
            v = *(const float4*)(nf + (size_t)(nb + node) * NODE_IN + kc);
        uint2 u2 = make_uint2(pk2(v.x, v.y), pk2(v.z, v.w));
        *(uint2*)&sA[node * 136 + kc] = u2;
    }
    __syncthreads();

    f32x4 acc[2][4];
    #pragma unroll
    for (int m = 0; m < 2; m++)
        #pragma unroll
        for (int tt = 0; tt < 4; tt++) acc[m][tt] = (f32x4){0.f, 0.f, 0.f, 0.f};

    #pragma unroll
    for (int ks = 0; ks < 4; ks++) {
        bf16x8 a0 = *(const bf16x8*)&sA[n15 * 136 + ks * 32 + q * 8];
        bf16x8 a1 = *(const bf16x8*)&sA[(16 + n15) * 136 + ks * 32 + q * 8];
        #pragma unroll
        for (int tt = 0; tt < 4; tt++) {
            int nt = (tt < 2) ? (2 * w + tt) : (8 + 2 * w + (tt - 2));
            bf16x8 b = *(const bf16x8*)(bfrag + ((size_t)(nt * 4 + ks) * 64 + lane) * 8);
            acc[0][tt] = __builtin_amdgcn_mfma_f32_16x16x32_bf16(a0, b, acc[0][tt], 0, 0, 0);
            acc[1][tt] = __builtin_amdgcn_mfma_f32_16x16x32_bf16(a1, b, acc[1][tt], 0, 0, 0);
        }
    }

    // el/er for head w (all waves busy)
    {
        float al0 = attn_l[w * 32 + n15];
        float al1 = attn_l[w * 32 + 16 + n15];
        float ar0 = attn_r[w * 32 + n15];
        float ar1 = attn_r[w * 32 + 16 + n15];
        #pragma unroll
        for (int m = 0; m < 2; m++) {
            #pragma unroll
            for (int r = 0; r < 4; r++) {
                float fa = acc[m][0][r], fb = acc[m][1][r];
                float elp = fa * al0 + fb * al1;
                float erp = fa * ar0 + fb * ar1;
                elp += __shfl_xor(elp, 1); erp += __shfl_xor(erp, 1);
                elp += __shfl_xor(elp, 2); erp += __shfl_xor(erp, 2);
                elp += __shfl_xor(elp, 4); erp += __shfl_xor(erp, 4);
                elp += __shfl_xor(elp, 8); erp += __shfl_xor(erp, 8);
                int node = nb + m * 16 + q * 4 + r;
                if (n15 == 0 && node < V_N) {
                    el[node * 4 + w] = elp;
                    er[node * 4 + w] = erp;
                }
            }
        }
    }
    // ft f16 store, head-major
    #pragma unroll
    for (int m = 0; m < 2; m++)
        #pragma unroll
        for (int r = 0; r < 4; r++) {
            int node = nb + m * 16 + q * 4 + r;
            if (node < V_N)
                ftw[(size_t)node * 64 + w * 16 + n15] =
                    pkh2(acc[m][0][r], acc[m][1][r]);
        }
    __syncthreads();

    // residual: wave w stages cols 32w..32w+31 (tt=2,3)
    #pragma unroll
    for (int m = 0; m < 2; m++)
        #pragma unroll
        for (int tt = 2; tt < 4; tt++)
            #pragma unroll
            for (int r = 0; r < 4; r++)
                sSf[(m * 16 + q * 4 + r) * 140 + w * 32 + (tt - 2) * 16 + n15] =
                    acc[m][tt][r];
    __syncthreads();
    #pragma unroll
    for (int i = 0; i < 4; i++) {
        int u = t + i * 256;
        int node = u >> 5, c4 = (u & 31) * 4;
        if (nb + node < V_N) {
            float4 v = *(float4*)&sSf[node * 140 + c4];
            float4 b4 = *(const float4*)(bias + c4);
            v.x += b4.x; v.y += b4.y; v.z += b4.z; v.w += b4.w;
            *(float4*)(out + (size_t)(nb + node) * HF + c4) = v;
        }
    }
}

// Cooperative fused CSR build + edge scatter.
// G=1024 blocks x 256 thr, 4 blocks/CU co-resident (launch_bounds(256,4)).
// Phase 0: zero deg, watt->LDS. Phase B: per 256-edge tile, coalesced ee +
// rank/lee in registers. Phase C: 2-level scan. Phase D: register scatter.
__global__ __launch_bounds__(256, 4) void k_build(
    const float* __restrict__ ef, const int* __restrict__ src,
    const int* __restrict__ dst, const float* __restrict__ We,
    const float* __restrict__ attn_e, const float* __restrict__ el,
    int* __restrict__ deg, int* __restrict__ rowp,
    int* __restrict__ bsum, uint4* __restrict__ rec)
{
    cg::grid_group grid = cg::this_grid();
    __shared__ float sw[64];
    __shared__ __align__(16) float see[256][4];
    __shared__ int shs[256];
    const int t = threadIdx.x;
    const int b = blockIdx.x;
    const int G = gridDim.x;

    if (t < 64) {
        int k = t >> 2, h = t & 3;
        float s = 0.f;
        #pragma unroll
        for (int f = 0; f < 32; f++)
            s += We[k * HF + h * 32 + f] * attn_e[h * 32 + f];
        sw[t] = s;                     // sw[k*4+h]
    }
    for (int i = b * 256 + t; i < V_N; i += G * 256) deg[i] = 0;
    grid.sync();

    const int lane = t & 63, w = t >> 6;
    const int k0 = (lane & 3) * 4;
    int sv[4], dv[4], rv[4];
    unsigned lA[4], lB[4];
    int ntile = 0;

    for (int tile = b; tile < E_N / 256; tile += G) {
        const int base = tile * 256;
        // quad (4 lanes) per edge: fully coalesced 16B/lane ef reads
        #pragma unroll
        for (int r = 0; r < 4; r++) {
            int le = w * 64 + r * 16 + (lane >> 2);
            float4 v = *(const float4*)(ef + (size_t)(base + le) * EDGE_IN + k0);
            float e0 = 0.f, e1 = 0.f, e2 = 0.f, e3 = 0.f;
            float vv[4] = {v.x, v.y, v.z, v.w};
            #pragma unroll
            for (int j = 0; j < 4; j++) {
                int k = k0 + j;
                e0 += vv[j] * sw[k * 4 + 0];
                e1 += vv[j] * sw[k * 4 + 1];
                e2 += vv[j] * sw[k * 4 + 2];
                e3 += vv[j] * sw[k * 4 + 3];
            }
            e0 += __shfl_xor(e0, 1); e1 += __shfl_xor(e1, 1);
            e2 += __shfl_xor(e2, 1); e3 += __shfl_xor(e3, 1);
            e0 += __shfl_xor(e0, 2); e1 += __shfl_xor(e1, 2);
            e2 += __shfl_xor(e2, 2); e3 += __shfl_xor(e3, 2);
            if ((lane & 3) == 0) {
                float4 o = {e0, e1, e2, e3};
                *(float4*)&see[le][0] = o;
            }
        }
        __syncthreads();
        int e = base + t;
        int s = src[e], d = dst[e];
        float4 ee = *(float4*)&see[t][0];
        float4 el4 = *(const float4*)(el + (size_t)s * 4);
        sv[ntile] = s;
        dv[ntile] = d;
        rv[ntile] = atomicAdd(&deg[d], 1);
        lA[ntile] = pk2(el4.x + ee.x, el4.y + ee.y);
        lB[ntile] = pk2(el4.z + ee.z, el4.w + ee.w);
        ntile++;
        __syncthreads();
    }
    grid.sync();

    // scan level 1: per-block exclusive scan of deg
    if (b < NB_SCAN) {
        int i = b * 256 + t;
        int v = (i < V_N) ? deg[i] : 0;
        shs[t] = v;
        __syncthreads();
        #pragma unroll
        for (int off = 1; off < 256; off <<= 1) {
            int u = (t >= off) ? shs[t - off] : 0;
            __syncthreads();
            shs[t] += u;
            __syncthreads();
        }
        if (i < V_N) rowp[i] = shs[t] - v;
        if (t == 255) bsum[b] = shs[255];
    }
    grid.sync();
    // scan level 2: add block offsets (each block redundantly scans bsum)
    if (b < NB_SCAN) {
        int v = (t < NB_SCAN) ? bsum[t] : 0;
        shs[t] = v;
        __syncthreads();
        #pragma unroll
        for (int off = 1; off < 256; off <<= 1) {
            int u = (t >= off) ? shs[t - off] : 0;
            __syncthreads();
            shs[t] += u;
            __syncthreads();
        }
        int boff = (b == 0) ? 0 : shs[b - 1];
        int i = b * 256 + t;
        if (i < V_N) rowp[i] += boff;
        if (i == 0) rowp[V_N] = E_N;
    }
    grid.sync();

    // scatter records straight from registers
    #pragma unroll
    for (int u = 0; u < 4; u++) {
        if (u < ntile) {
            int p = rowp[dv[u]] + rv[u];
            uint4 rr;
            rr.x = (unsigned)sv[u];
            rr.y = lA[u];
            rr.z = lB[u];
            rr.w = 0;
            rec[p] = rr;
        }
    }
}

// One wave per dst, single pass: U = sum ex*ft (f16), s = sum ex; normalize
// at end. 8 edges/inner-iter. ftw head-major: lane li's uint4 -> head li>>2.
__global__ __launch_bounds__(256) void k_gather(
    const int* __restrict__ row, const uint4* __restrict__ rec,
    const float* __restrict__ er,
    const unsigned* __restrict__ ftw, float* __restrict__ out)
{
    __shared__ unsigned aw[4][64][4];    // per edge: dup-half2 ex per head
    const int lane = threadIdx.x & 63;
    const int wid  = threadIdx.x >> 6;
    const int d = blockIdx.x * 4 + wid;
    if (d >= V_N) return;
    const int n0 = row[d];
    const int deg = row[d + 1] - n0;
    if (deg == 0) return;

    const float4 er4 = *(const float4*)(er + (size_t)d * 4);

    const int qw = lane >> 4, li = lane & 15;
    const int head = li >> 2;
    float4 s4 = {0.f, 0.f, 0.f, 0.f};
    __half2 ha0 = u2h(0u), ha1 = u2h(0u), ha2 = u2h(0u), ha3 = u2h(0u);
    __half2 hb0 = u2h(0u), hb1 = u2h(0u), hb2 = u2h(0u), hb3 = u2h(0u);

    for (int i0 = 0; i0 < deg; i0 += 64) {
        int chunk = min(64, deg - i0);
        int si = 0;
        float4 ex = {0.f, 0.f, 0.f, 0.f};
        if (lane < chunk) {
            uint4 r = rec[n0 + i0 + lane];
            si = (int)r.x;
            float x0 = bflo(r.y) + er4.x;
            float x1 = bfhi(r.y) + er4.y;
            float x2 = bflo(r.z) + er4.z;
            float x3 = bfhi(r.z) + er4.w;
            x0 = x0 >= 0.f ? x0 : NEG_SLOPE * x0;
            x1 = x1 >= 0.f ? x1 : NEG_SLOPE * x1;
            x2 = x2 >= 0.f ? x2 : NEG_SLOPE * x2;
            x3 = x3 >= 0.f ? x3 : NEG_SLOPE * x3;
            ex.x = __expf(x0); ex.y = __expf(x1);
            ex.z = __expf(x2); ex.w = __expf(x3);
            s4.x += ex.x; s4.y += ex.y; s4.z += ex.z; s4.w += ex.w;
        }
        uint4 ap;
        ap.x = pkh2(ex.x, ex.x); ap.y = pkh2(ex.y, ex.y);
        ap.z = pkh2(ex.z, ex.z); ap.w = pkh2(ex.w, ex.w);
        *(uint4*)&aw[wid][lane][0] = ap;
        asm volatile("s_waitcnt lgkmcnt(0)" ::: "memory");

        int iters = (chunk + 7) & ~7;
        for (int j = 0; j < iters; j += 8) {
            int jq0 = j + qw, jq1 = j + qw + 4;
            int sidx0 = __shfl(si, jq0);        // jq>=chunk -> si=0, ex=0
            int sidx1 = __shfl(si, jq1);
            unsigned au0 = aw[wid][jq0][head];
            unsigned au1 = aw[wid][jq1][head];
            uint4 wv0 = *(const uint4*)(ftw + (size_t)sidx0 * 64 + li * 4);
            uint4 wv1 = *(const uint4*)(ftw + (size_t)sidx1 * 64 + li * 4);
            ha0 = __hfma2(u2h(wv0.x), u2h(au0), ha0);
            ha1 = __hfma2(u2h(wv0.y), u2h(au0), ha1);
            ha2 = __hfma2(u2h(wv0.z), u2h(au0), ha2);
            ha3 = __hfma2(u2h(wv0.w), u2h(au0), ha3);
            hb0 = __hfma2(u2h(wv1.x), u2h(au1), hb0);
            hb1 = __hfma2(u2h(wv1.y), u2h(au1), hb1);
            hb2 = __hfma2(u2h(wv1.z), u2h(au1), hb2);
            hb3 = __hfma2(u2h(wv1.w), u2h(au1), hb3);
        }
    }
    #pragma unroll
    for (int off = 1; off < 64; off <<= 1) {
        s4.x += __shfl_xor(s4.x, off);
        s4.y += __shfl_xor(s4.y, off);
        s4.z += __shfl_xor(s4.z, off);
        s4.w += __shfl_xor(s4.w, off);
    }
    ha0 = __hadd2(ha0, hb0); ha1 = __hadd2(ha1, hb1);
    ha2 = __hadd2(ha2, hb2); ha3 = __hadd2(ha3, hb3);
    ha0 = __hadd2(ha0, u2h(__shfl_xor(h2u(ha0), 16)));
    ha1 = __hadd2(ha1, u2h(__shfl_xor(h2u(ha1), 16)));
    ha2 = __hadd2(ha2, u2h(__shfl_xor(h2u(ha2), 16)));
    ha3 = __hadd2(ha3, u2h(__shfl_xor(h2u(ha3), 16)));
    ha0 = __hadd2(ha0, u2h(__shfl_xor(h2u(ha0), 32)));
    ha1 = __hadd2(ha1, u2h(__shfl_xor(h2u(ha1), 32)));
    ha2 = __hadd2(ha2, u2h(__shfl_xor(h2u(ha2), 32)));
    ha3 = __hadd2(ha3, u2h(__shfl_xor(h2u(ha3), 32)));
    if (qw == 0) {
        float rsv = 1.f / (head == 0 ? s4.x : head == 1 ? s4.y :
                           head == 2 ? s4.z : s4.w);
        float* op = out + (size_t)d * HF + head * 32 + (li & 3) * 4;
        float4 r0 = *(float4*)op;
        r0.x += __low2float(ha0) * rsv; r0.y += __low2float(ha1) * rsv;
        r0.z += __low2float(ha2) * rsv; r0.w += __low2float(ha3) * rsv;
        *(float4*)op = r0;
        float4 r1 = *(float4*)(op + 16);
        r1.x += __high2float(ha0) * rsv; r1.y += __high2float(ha1) * rsv;
        r1.z += __high2float(ha2) * rsv; r1.w += __high2float(ha3) * rsv;
        *(float4*)(op + 16) = r1;
    }
}

extern "C" void kernel_launch(void* const* d_in, const int* in_sizes, int n_in,
                              void* d_out, int out_size, void* d_ws, size_t ws_size,
                              hipStream_t stream) {
    const float* nf     = (const float*)d_in[0];
    const float* ef     = (const float*)d_in[1];
    const int*   src    = (const int*)d_in[2];
    const int*   dst    = (const int*)d_in[3];
    const float* Wn     = (const float*)d_in[4];
    const float* We     = (const float*)d_in[5];
    const float* attn_l = (const float*)d_in[6];
    const float* attn_r = (const float*)d_in[7];
    const float* attn_e = (const float*)d_in[8];
    const float* Wr     = (const float*)d_in[9];
    const float* bias   = (const float*)d_in[10];
    float* out = (float*)d_out;

    unsigned* wsw  = (unsigned*)d_ws;
    unsigned* ftw  = wsw + OFF_FT;
    float* el      = (float*)(wsw + OFF_EL);
    float* er      = (float*)(wsw + OFF_ER);
    int* deg       = (int*)(wsw + OFF_DEG);
    int* rowp      = (int*)(wsw + OFF_ROW);
    int* bsum      = (int*)(wsw + OFF_BSUM);
    uint4* rec     = (uint4*)(wsw + OFF_REC);
    unsigned* bfrag = wsw + OFF_BFRAG;

    k_prep<<<64, 256, 0, stream>>>(Wn, Wr, bfrag);
    k_node<<<(V_N + 31) / 32, 256, 0, stream>>>(nf, bfrag, attn_l, attn_r,
                                                bias, ftw, el, er, out);
    {
        void* args[] = {(void*)&ef, (void*)&src, (void*)&dst, (void*)&We,
                        (void*)&attn_e, (void*)&el, (void*)&deg, (void*)&rowp,
                        (void*)&bsum, (void*)&rec};
        hipLaunchCooperativeKernel((void*)k_build, dim3(1024), dim3(256),
                                   args, 0, stream);
    }
    k_gather<<<(V_N + 3) / 4, 256, 0, stream>>>(rowp, rec, er, ftw, out);
}

// Round 11
// 255.063 us; speedup vs baseline: 2.3888x; 2.3888x over previous
//
#include <hip/hip_runtime.h>
#include <hip/hip_fp16.h>
#include <cstdint>

#define V_N 50000
#define E_N 800000
#define NODE_IN 128
#define EDGE_IN 16
#define HF 128
#define NEG_SLOPE 0.2f
#define NB_SCAN 196   // ceil(50000/256)

// ---- workspace layout (4-byte word offsets) ----
#define OFF_FT    0         // V*64 words (f16 ft, head-major layout)
#define OFF_EL    3200000   // V*4
#define OFF_ER    3400000   // V*4
#define OFF_DEG   3600000   // V ints
#define OFF_ROW   3650000   // V+1 ints (+pad)
#define OFF_ST    3700004   // 196 ull (8B-aligned: 3700004*4 % 8 == 0)
#define OFF_RANK  3700400   // E ints
#define OFF_REC   4500400   // E*4 words (uint4; 16B-aligned)
#define OFF_BFRAG 7700400   // 16384 words
// total ~7.72M words = 30.9 MB

typedef short bf16x8 __attribute__((ext_vector_type(8)));
typedef float f32x4 __attribute__((ext_vector_type(4)));

__device__ __forceinline__ unsigned short f2bf(float f) {
    unsigned u = __float_as_uint(f);
    u += 0x7fffu + ((u >> 16) & 1u);   // round-to-nearest-even
    return (unsigned short)(u >> 16);
}
__device__ __forceinline__ unsigned pk2(float lo, float hi) {
    return (unsigned)f2bf(lo) | ((unsigned)f2bf(hi) << 16);
}
__device__ __forceinline__ float bflo(unsigned w) { return __uint_as_float(w << 16); }
__device__ __forceinline__ float bfhi(unsigned w) { return __uint_as_float(w & 0xffff0000u); }

typedef __fp16 fp16x2 __attribute__((ext_vector_type(2)));
__device__ __forceinline__ unsigned pkh2(float a, float b) {
    fp16x2 h = __builtin_amdgcn_cvt_pkrtz(a, b);   // v_cvt_pkrtz_f16_f32
    return __builtin_bit_cast(unsigned, h);
}
__device__ __forceinline__ __half2 u2h(unsigned u) {
    return __builtin_bit_cast(__half2, u);
}
__device__ __forceinline__ unsigned h2u(__half2 h) {
    return __builtin_bit_cast(unsigned, h);
}

// k_prep: zero deg + scan-status; bf16 fragment conversion of [Wn|Wr].
__global__ void k_prep(const float* __restrict__ Wn,
                       const float* __restrict__ Wr,
                       unsigned* __restrict__ bfrag,
                       int* __restrict__ deg,
                       unsigned long long* __restrict__ st) {
    int g = blockIdx.x * 256 + threadIdx.x;
    for (int i = g; i < V_N; i += 16384) deg[i] = 0;
    if (g < NB_SCAN) st[g] = 0ULL;
    if (g < 16384) {
        int c    = g >> 8;
        int lane = (g >> 2) & 63;
        int jp   = g & 3;
        int nt = c >> 2, ks = c & 3;
        int col = nt * 16 + (lane & 15);
        int k   = ks * 32 + (lane >> 4) * 8 + jp * 2;
        const float* W = (col < 128) ? Wn : Wr;
        int cc = col & 127;
        float x0 = W[(size_t)k * 128 + cc];
        float x1 = W[(size_t)(k + 1) * 128 + cc];
        bfrag[g] = pk2(x0, x1);
    }
}

// Node kernel (MFMA): 32 nodes x 256 cols per block; wave w == head w.
// ftw head-major: uint idx = node*64 + head*16 + n15 (f16 pair tt=0,1)
__global__ __launch_bounds__(256) void k_node(
    const float* __restrict__ nf, const unsigned* __restrict__ bfragw,
    const float* __restrict__ attn_l, const float* __restrict__ attn_r,
    const float* __restrict__ bias,
    unsigned* __restrict__ ftw, float* __restrict__ el,
    float* __restrict__ er, float* __restrict__ out)
{
    __shared__ __align__(16) float sSf[32 * 140];
    unsigned short* sA = (unsigned short*)sSf;      // stride 136 bf16/row

    const int t = threadIdx.x;
    const int lane = t & 63;
    const int w = t >> 6;                            // == head
    const int nb = blockIdx.x * 32;
    const int n15 = lane & 15;
    const int q = lane >> 4;
    const unsigned short* bfrag = (const unsigned short*)bfragw;

    #pragma unroll
    for (int i = 0; i < 4; i++) {
        int f = t + i * 256;
        int node = f >> 5;
        int kc = (f & 31) * 4;
        float4 v = {0.f, 0.f, 0.f, 0.f};
        if (nb + node < V_N)
            v = *(const float4*)(nf + (size_t)(nb + node) * NODE_IN + kc);
        uint2 u2 = make_uint2(pk2(v.x, v.y), pk2(v.z, v.w));
        *(uint2*)&sA[node * 136 + kc] = u2;
    }
    __syncthreads();

    f32x4 acc[2][4];
    #pragma unroll
    for (int m = 0; m < 2; m++)
        #pragma unroll
        for (int tt = 0; tt < 4; tt++) acc[m][tt] = (f32x4){0.f, 0.f, 0.f, 0.f};

    #pragma unroll
    for (int ks = 0; ks < 4; ks++) {
        bf16x8 a0 = *(const bf16x8*)&sA[n15 * 136 + ks * 32 + q * 8];
        bf16x8 a1 = *(const bf16x8*)&sA[(16 + n15) * 136 + ks * 32 + q * 8];
        #pragma unroll
        for (int tt = 0; tt < 4; tt++) {
            int nt = (tt < 2) ? (2 * w + tt) : (8 + 2 * w + (tt - 2));
            bf16x8 b = *(const bf16x8*)(bfrag + ((size_t)(nt * 4 + ks) * 64 + lane) * 8);
            acc[0][tt] = __builtin_amdgcn_mfma_f32_16x16x32_bf16(a0, b, acc[0][tt], 0, 0, 0);
            acc[1][tt] = __builtin_amdgcn_mfma_f32_16x16x32_bf16(a1, b, acc[1][tt], 0, 0, 0);
        }
    }

    // el/er for head w (all waves busy)
    {
        float al0 = attn_l[w * 32 + n15];
        float al1 = attn_l[w * 32 + 16 + n15];
        float ar0 = attn_r[w * 32 + n15];
        float ar1 = attn_r[w * 32 + 16 + n15];
        #pragma unroll
        for (int m = 0; m < 2; m++) {
            #pragma unroll
            for (int r = 0; r < 4; r++) {
                float fa = acc[m][0][r], fb = acc[m][1][r];
                float elp = fa * al0 + fb * al1;
                float erp = fa * ar0 + fb * ar1;
                elp += __shfl_xor(elp, 1); erp += __shfl_xor(erp, 1);
                elp += __shfl_xor(elp, 2); erp += __shfl_xor(erp, 2);
                elp += __shfl_xor(elp, 4); erp += __shfl_xor(erp, 4);
                elp += __shfl_xor(elp, 8); erp += __shfl_xor(erp, 8);
                int node = nb + m * 16 + q * 4 + r;
                if (n15 == 0 && node < V_N) {
                    el[node * 4 + w] = elp;
                    er[node * 4 + w] = erp;
                }
            }
        }
    }
    // ft f16 store, head-major
    #pragma unroll
    for (int m = 0; m < 2; m++)
        #pragma unroll
        for (int r = 0; r < 4; r++) {
            int node = nb + m * 16 + q * 4 + r;
            if (node < V_N)
                ftw[(size_t)node * 64 + w * 16 + n15] =
                    pkh2(acc[m][0][r], acc[m][1][r]);
        }
    __syncthreads();

    // residual: wave w stages cols 32w..32w+31 (tt=2,3)
    #pragma unroll
    for (int m = 0; m < 2; m++)
        #pragma unroll
        for (int tt = 2; tt < 4; tt++)
            #pragma unroll
            for (int r = 0; r < 4; r++)
                sSf[(m * 16 + q * 4 + r) * 140 + w * 32 + (tt - 2) * 16 + n15] =
                    acc[m][tt][r];
    __syncthreads();
    #pragma unroll
    for (int i = 0; i < 4; i++) {
        int u = t + i * 256;
        int node = u >> 5, c4 = (u & 31) * 4;
        if (nb + node < V_N) {
            float4 v = *(float4*)&sSf[node * 140 + c4];
            float4 b4 = *(const float4*)(bias + c4);
            v.x += b4.x; v.y += b4.y; v.z += b4.z; v.w += b4.w;
            *(float4*)(out + (size_t)(nb + node) * HF + c4) = v;
        }
    }
}

// ---- hist: rank + deg, 4 edges/thread for MLP ----
__global__ void k_hist(const int* __restrict__ dst, int* __restrict__ deg,
                       int* __restrict__ rank) {
    int base = blockIdx.x * 1024 + threadIdx.x;
    #pragma unroll
    for (int u = 0; u < 4; u++) {
        int e = base + u * 256;
        if (e < E_N) rank[e] = atomicAdd(&deg[dst[e]], 1);
    }
}

// ---- single-dispatch decoupled-lookback exclusive scan of deg -> rowp ----
// st[b]: (status<<32)|value; status 1 = aggregate, 2 = inclusive prefix.
// 196 blocks <= grid capacity -> all co-resident, spin is safe.
__global__ __launch_bounds__(256) void k_scan(
    const int* __restrict__ deg, int* __restrict__ rowp,
    unsigned long long* __restrict__ st)
{
    __shared__ int sh[256];
    __shared__ int sexcl;
    int t = threadIdx.x, b = blockIdx.x;
    int i = b * 256 + t;
    int v = (i < V_N) ? deg[i] : 0;
    sh[t] = v;
    __syncthreads();
    #pragma unroll
    for (int off = 1; off < 256; off <<= 1) {
        int u = (t >= off) ? sh[t - off] : 0;
        __syncthreads();
        sh[t] += u;
        __syncthreads();
    }
    int agg = sh[255];
    if (t == 0) {
        if (b == 0) {
            atomicExch(&st[0], (2ULL << 32) | (unsigned)agg);
            sexcl = 0;
        } else {
            atomicExch(&st[b], (1ULL << 32) | (unsigned)agg);
            int excl = 0;
            int j = b - 1;
            while (true) {
                unsigned long long p = atomicAdd(&st[j], 0ULL);
                unsigned stat = (unsigned)(p >> 32);
                if (stat == 2u) { excl += (int)(unsigned)p; break; }
                if (stat == 1u) { excl += (int)(unsigned)p; j--; continue; }
                __builtin_amdgcn_s_sleep(1);
            }
            atomicExch(&st[b], (2ULL << 32) | (unsigned)(excl + agg));
            sexcl = excl;
        }
    }
    __syncthreads();
    int excl = sexcl;
    if (i < V_N) rowp[i] = excl + sh[t] - v;
    if (b == 0 && t == 0) rowp[V_N] = E_N;
}

// Streaming escatter, fully-coalesced ef reads (quad of lanes per edge),
// then 1 edge/thread scatter: record[p] = {src, lee01, lee23, 0} where
// lee = el[src] + ee (bf16). 800000 == 3125*256 exactly -> no guards.
__global__ __launch_bounds__(256) void k_escatter(
    const float* __restrict__ ef, const int* __restrict__ src,
    const int* __restrict__ dst, const int* __restrict__ rank,
    const int* __restrict__ rowp, const float* __restrict__ We,
    const float* __restrict__ attn_e,
    const float* __restrict__ el, uint4* __restrict__ rec)
{
    __shared__ float sw[64];
    __shared__ __align__(16) float see[256][4];
    const int t = threadIdx.x;
    if (t < 64) {
        int k = t >> 2, h = t & 3;
        float s = 0.f;
        #pragma unroll
        for (int f = 0; f < 32; f++)
            s += We[k * HF + h * 32 + f] * attn_e[h * 32 + f];
        sw[t] = s;
    }
    __syncthreads();
    const int base = blockIdx.x * 256;
    const int lane = t & 63, w = t >> 6;
    const int k0 = (lane & 3) * 4;

    #pragma unroll
    for (int r = 0; r < 4; r++) {
        int le = w * 64 + r * 16 + (lane >> 2);
        float4 v = *(const float4*)(ef + (size_t)(base + le) * EDGE_IN + k0);
        float e0 = 0.f, e1 = 0.f, e2 = 0.f, e3 = 0.f;
        float vv[4] = {v.x, v.y, v.z, v.w};
        #pragma unroll
        for (int j = 0; j < 4; j++) {
            int k = k0 + j;
            e0 += vv[j] * sw[k * 4 + 0];
            e1 += vv[j] * sw[k * 4 + 1];
            e2 += vv[j] * sw[k * 4 + 2];
            e3 += vv[j] * sw[k * 4 + 3];
        }
        e0 += __shfl_xor(e0, 1); e1 += __shfl_xor(e1, 1);
        e2 += __shfl_xor(e2, 1); e3 += __shfl_xor(e3, 1);
        e0 += __shfl_xor(e0, 2); e1 += __shfl_xor(e1, 2);
        e2 += __shfl_xor(e2, 2); e3 += __shfl_xor(e3, 2);
        if ((lane & 3) == 0) {
            float4 o = {e0, e1, e2, e3};
            *(float4*)&see[le][0] = o;
        }
    }
    __syncthreads();

    int e = base + t;
    int s = src[e], d = dst[e];
    int p = rowp[d] + rank[e];
    float4 ee = *(float4*)&see[t][0];
    float4 el4 = *(const float4*)(el + (size_t)s * 4);
    uint4 rr;
    rr.x = (unsigned)s;
    rr.y = pk2(el4.x + ee.x, el4.y + ee.y);
    rr.z = pk2(el4.z + ee.z, el4.w + ee.w);
    rr.w = 0;
    rec[p] = rr;
}

// One wave per dst, single pass: U = sum ex*ft (f16), s = sum ex; normalize
// at end. 8 edges/inner-iter. ftw head-major: lane li's uint4 -> head li>>2.
__global__ __launch_bounds__(256) void k_gather(
    const int* __restrict__ row, const uint4* __restrict__ rec,
    const float* __restrict__ er,
    const unsigned* __restrict__ ftw, float* __restrict__ out)
{
    __shared__ unsigned aw[4][64][4];    // per edge: dup-half2 ex per head
    const int lane = threadIdx.x & 63;
    const int wid  = threadIdx.x >> 6;
    const int d = blockIdx.x * 4 + wid;
    if (d >= V_N) return;
    const int n0 = row[d];
    const int deg = row[d + 1] - n0;
    if (deg == 0) return;

    const float4 er4 = *(const float4*)(er + (size_t)d * 4);

    const int qw = lane >> 4, li = lane & 15;
    const int head = li >> 2;
    float4 s4 = {0.f, 0.f, 0.f, 0.f};
    __half2 ha0 = u2h(0u), ha1 = u2h(0u), ha2 = u2h(0u), ha3 = u2h(0u);
    __half2 hb0 = u2h(0u), hb1 = u2h(0u), hb2 = u2h(0u), hb3 = u2h(0u);

    for (int i0 = 0; i0 < deg; i0 += 64) {
        int chunk = min(64, deg - i0);
        int si = 0;
        float4 ex = {0.f, 0.f, 0.f, 0.f};
        if (lane < chunk) {
            uint4 r = rec[n0 + i0 + lane];
            si = (int)r.x;
            float x0 = bflo(r.y) + er4.x;
            float x1 = bfhi(r.y) + er4.y;
            float x2 = bflo(r.z) + er4.z;
            float x3 = bfhi(r.z) + er4.w;
            x0 = x0 >= 0.f ? x0 : NEG_SLOPE * x0;
            x1 = x1 >= 0.f ? x1 : NEG_SLOPE * x1;
            x2 = x2 >= 0.f ? x2 : NEG_SLOPE * x2;
            x3 = x3 >= 0.f ? x3 : NEG_SLOPE * x3;
            ex.x = __expf(x0); ex.y = __expf(x1);
            ex.z = __expf(x2); ex.w = __expf(x3);
            s4.x += ex.x; s4.y += ex.y; s4.z += ex.z; s4.w += ex.w;
        }
        uint4 ap;
        ap.x = pkh2(ex.x, ex.x); ap.y = pkh2(ex.y, ex.y);
        ap.z = pkh2(ex.z, ex.z); ap.w = pkh2(ex.w, ex.w);
        *(uint4*)&aw[wid][lane][0] = ap;
        asm volatile("s_waitcnt lgkmcnt(0)" ::: "memory");

        int iters = (chunk + 7) & ~7;
        for (int j = 0; j < iters; j += 8) {
            int jq0 = j + qw, jq1 = j + qw + 4;
            int sidx0 = __shfl(si, jq0);        // jq>=chunk -> si=0, ex=0
            int sidx1 = __shfl(si, jq1);
            unsigned au0 = aw[wid][jq0][head];
            unsigned au1 = aw[wid][jq1][head];
            uint4 wv0 = *(const uint4*)(ftw + (size_t)sidx0 * 64 + li * 4);
            uint4 wv1 = *(const uint4*)(ftw + (size_t)sidx1 * 64 + li * 4);
            ha0 = __hfma2(u2h(wv0.x), u2h(au0), ha0);
            ha1 = __hfma2(u2h(wv0.y), u2h(au0), ha1);
            ha2 = __hfma2(u2h(wv0.z), u2h(au0), ha2);
            ha3 = __hfma2(u2h(wv0.w), u2h(au0), ha3);
            hb0 = __hfma2(u2h(wv1.x), u2h(au1), hb0);
            hb1 = __hfma2(u2h(wv1.y), u2h(au1), hb1);
            hb2 = __hfma2(u2h(wv1.z), u2h(au1), hb2);
            hb3 = __hfma2(u2h(wv1.w), u2h(au1), hb3);
        }
    }
    #pragma unroll
    for (int off = 1; off < 64; off <<= 1) {
        s4.x += __shfl_xor(s4.x, off);
        s4.y += __shfl_xor(s4.y, off);
        s4.z += __shfl_xor(s4.z, off);
        s4.w += __shfl_xor(s4.w, off);
    }
    ha0 = __hadd2(ha0, hb0); ha1 = __hadd2(ha1, hb1);
    ha2 = __hadd2(ha2, hb2); ha3 = __hadd2(ha3, hb3);
    ha0 = __hadd2(ha0, u2h(__shfl_xor(h2u(ha0), 16)));
    ha1 = __hadd2(ha1, u2h(__shfl_xor(h2u(ha1), 16)));
    ha2 = __hadd2(ha2, u2h(__shfl_xor(h2u(ha2), 16)));
    ha3 = __hadd2(ha3, u2h(__shfl_xor(h2u(ha3), 16)));
    ha0 = __hadd2(ha0, u2h(__shfl_xor(h2u(ha0), 32)));
    ha1 = __hadd2(ha1, u2h(__shfl_xor(h2u(ha1), 32)));
    ha2 = __hadd2(ha2, u2h(__shfl_xor(h2u(ha2), 32)));
    ha3 = __hadd2(ha3, u2h(__shfl_xor(h2u(ha3), 32)));
    if (qw == 0) {
        float rsv = 1.f / (head == 0 ? s4.x : head == 1 ? s4.y :
                           head == 2 ? s4.z : s4.w);
        float* op = out + (size_t)d * HF + head * 32 + (li & 3) * 4;
        float4 r0 = *(float4*)op;
        r0.x += __low2float(ha0) * rsv; r0.y += __low2float(ha1) * rsv;
        r0.z += __low2float(ha2) * rsv; r0.w += __low2float(ha3) * rsv;
        *(float4*)op = r0;
        float4 r1 = *(float4*)(op + 16);
        r1.x += __high2float(ha0) * rsv; r1.y += __high2float(ha1) * rsv;
        r1.z += __high2float(ha2) * rsv; r1.w += __high2float(ha3) * rsv;
        *(float4*)(op + 16) = r1;
    }
}

extern "C" void kernel_launch(void* const* d_in, const int* in_sizes, int n_in,
                              void* d_out, int out_size, void* d_ws, size_t ws_size,
                              hipStream_t stream) {
    const float* nf     = (const float*)d_in[0];
    const float* ef     = (const float*)d_in[1];
    const int*   src    = (const int*)d_in[2];
    const int*   dst    = (const int*)d_in[3];
    const float* Wn     = (const float*)d_in[4];
    const float* We     = (const float*)d_in[5];
    const float* attn_l = (const float*)d_in[6];
    const float* attn_r = (const float*)d_in[7];
    const float* attn_e = (const float*)d_in[8];
    const float* Wr     = (const float*)d_in[9];
    const float* bias   = (const float*)d_in[10];
    float* out = (float*)d_out;

    unsigned* wsw  = (unsigned*)d_ws;
    unsigned* ftw  = wsw + OFF_FT;
    float* el      = (float*)(wsw + OFF_EL);
    float* er      = (float*)(wsw + OFF_ER);
    int* deg       = (int*)(wsw + OFF_DEG);
    int* rowp      = (int*)(wsw + OFF_ROW);
    unsigned long long* st = (unsigned long long*)(wsw + OFF_ST);
    int* rank      = (int*)(wsw + OFF_RANK);
    uint4* rec     = (uint4*)(wsw + OFF_REC);
    unsigned* bfrag = wsw + OFF_BFRAG;

    k_prep<<<64, 256, 0, stream>>>(Wn, Wr, bfrag, deg, st);
    k_hist<<<(E_N + 1023) / 1024, 256, 0, stream>>>(dst, deg, rank);
    k_scan<<<NB_SCAN, 256, 0, stream>>>(deg, rowp, st);
    k_node<<<(V_N + 31) / 32, 256, 0, stream>>>(nf, bfrag, attn_l, attn_r,
                                                bias, ftw, el, er, out);
    k_escatter<<<E_N / 256, 256, 0, stream>>>(ef, src, dst, rank, rowp,
                                              We, attn_e, el, rec);
    k_gather<<<(V_N + 3) / 4, 256, 0, stream>>>(rowp, rec, er, ftw, out);
}